// Round 2
// baseline (293.734 us; speedup 1.0000x reference)
//
#include <hip/hip_runtime.h>

// out[o] = AND over i of (x[i] || w[o][i]==0)
//        = NOT( EXISTS i : w[o][i]!=0 && x[i]==0 )
//
// One 64-lane wave per output row, early-exit on first violating 256-element
// chunk. Bit-level nonzero test on both w and x so it works whether the
// harness delivers x as int32 or float32 (false == all-zero bits either way;
// values are only 0/1 so no -0.0 hazard).
__global__ __launch_bounds__(256) void hard_and_kernel(
    const int* __restrict__ w,   // [OUT*IN] float32 bit-pattern; nonzero bits = true
    const int* __restrict__ x,   // [IN]     int32/float32 bit-pattern; nonzero bits = true
    float* __restrict__ out,     // [OUT]    1.0f = true, 0.0f = false
    int IN, int OUT)
{
    const int wave = (int)((blockIdx.x * blockDim.x + threadIdx.x) >> 6);
    const int lane = threadIdx.x & 63;
    if (wave >= OUT) return;

    const long long row_base = (long long)wave * IN;

    bool alive = true;
    // 256 elements per wave-iteration: each lane owns 4 consecutive ints (16B).
    for (int base = 0; base < IN; base += 256) {
        const int idx = base + lane * 4;
        bool viol = false;
        if (idx + 3 < IN) {
            const int4 wv = *reinterpret_cast<const int4*>(&w[row_base + idx]);
            const int4 xv = *reinterpret_cast<const int4*>(&x[idx]);
            viol = (wv.x && !xv.x) || (wv.y && !xv.y) ||
                   (wv.z && !xv.z) || (wv.w && !xv.w);
        } else {
            for (int j = 0; j < 4; ++j) {
                int ii = idx + j;
                if (ii < IN) viol |= (w[row_base + ii] != 0) && (x[ii] == 0);
            }
        }
        if (__any(viol)) { alive = false; break; }
    }
    if (lane == 0) out[wave] = alive ? 1.0f : 0.0f;
}

extern "C" void kernel_launch(void* const* d_in, const int* in_sizes, int n_in,
                              void* d_out, int out_size, void* d_ws, size_t ws_size,
                              hipStream_t stream) {
    const int* w = (const int*)d_in[0];   // weights float32 viewed as bits
    const int* x = (const int*)d_in[1];   // x bool -> int32 (or float32) viewed as bits
    float* out = (float*)d_out;

    const int OUT = out_size;             // 8192
    const int IN  = in_sizes[1];          // 8192

    const int threads = 256;              // 4 waves/block
    const int wavesPerBlock = threads / 64;
    const int blocks = (OUT + wavesPerBlock - 1) / wavesPerBlock;

    hard_and_kernel<<<blocks, threads, 0, stream>>>(w, x, out, IN, OUT);
}

// Round 3
// 291.246 us; speedup vs baseline: 1.0085x; 1.0085x over previous
//
#include <hip/hip_runtime.h>

// out[o] = AND over i of (x[i] || w[o][i]==0)
//        = NOT( EXISTS i : w[o][i]!=0 && x[i]==0 )
//
// One 64-lane wave per output row. Each iteration probes 64 consecutive
// elements (1 dword/lane, fully coalesced 256B per wave) and ballots for a
// violation. With P(violation)=0.25/elem on this distribution, a row exits
// on its first 64-elem chunk with prob 1-0.75^64 ~= 1-1e-8, so total HBM
// touch is ~2 MB of the 268 MB matrix. Loop remains correct for any input.
__global__ __launch_bounds__(256) void hard_and_kernel(
    const int* __restrict__ w,   // [OUT*IN] float32 bit-pattern; nonzero = true
    const int* __restrict__ x,   // [IN]     int32/float32 bit-pattern; nonzero = true
    float* __restrict__ out,     // [OUT]    1.0f = true, 0.0f = false
    int IN, int OUT)
{
    const int wave = (int)((blockIdx.x * blockDim.x + threadIdx.x) >> 6);
    const int lane = threadIdx.x & 63;
    if (wave >= OUT) return;

    const long long row_base = (long long)wave * IN;

    bool alive = true;
    for (int base = 0; base < IN; base += 64) {
        const int idx = base + lane;
        bool viol = false;
        if (idx < IN) {
            const int wv = w[row_base + idx];
            const int xv = x[idx];
            viol = (wv != 0) && (xv == 0);
        }
        if (__any(viol)) { alive = false; break; }
    }
    if (lane == 0) out[wave] = alive ? 1.0f : 0.0f;
}

extern "C" void kernel_launch(void* const* d_in, const int* in_sizes, int n_in,
                              void* d_out, int out_size, void* d_ws, size_t ws_size,
                              hipStream_t stream) {
    const int* w = (const int*)d_in[0];   // weights float32 viewed as bits
    const int* x = (const int*)d_in[1];   // x viewed as bits (int32/float32 both ok)
    float* out = (float*)d_out;

    const int OUT = out_size;             // 8192
    const int IN  = in_sizes[1];          // 8192

    const int threads = 256;              // 4 waves/block
    const int wavesPerBlock = threads / 64;
    const int blocks = (OUT + wavesPerBlock - 1) / wavesPerBlock;

    hard_and_kernel<<<blocks, threads, 0, stream>>>(w, x, out, IN, OUT);
}